// Round 1
// baseline (559.604 us; speedup 1.0000x reference)
//
#include <hip/hip_runtime.h>
#include <hip/hip_bf16.h>

#define T_TOKENS 2048
#define H_DIM    2048
#define I_DIM    1408
#define E_NUM    8

typedef __bf16 bf16;
typedef __attribute__((ext_vector_type(4))) __bf16  bf16x4;
typedef __attribute__((ext_vector_type(8))) __bf16  bf16x8;
typedef __attribute__((ext_vector_type(4))) float   floatx4;

// ---------------- ws layout (bytes) ----------------
// counts:  [0, 32)
// lists:   [256, 256+65536)            int,   E*T entries = (token<<1 | slot)
// wlists:  [65792, 65792+65536)        float, E*T routing weights
// act:     [262144, +11534336)         bf16,  [2T][I]  indexed by pair=(t*2+s)
// tmp:     [11796480, +33554432)       f32,   [2T][H]  per-slot partial outputs
static const size_t OFF_COUNTS = 0;
static const size_t OFF_LISTS  = 256;
static const size_t OFF_WLISTS = OFF_LISTS + (size_t)T_TOKENS * E_NUM * 4;
static const size_t OFF_ACT    = 262144;
static const size_t OFF_TMP    = OFF_ACT + (size_t)2 * T_TOKENS * I_DIM * 2;

// ---------------- routing ----------------
__global__ void router_kernel(const float* __restrict__ logits,
                              int* __restrict__ counts,
                              int* __restrict__ lists,
                              float* __restrict__ wlists)
{
    int t = blockIdx.x * blockDim.x + threadIdx.x;
    if (t >= T_TOKENS) return;
    const float* l = logits + (size_t)t * E_NUM;
    float v0 = -1e30f, v1 = -1e30f;
    int i0 = 0, i1 = 0;
    #pragma unroll
    for (int e = 0; e < E_NUM; ++e) {
        float v = l[e];
        if (v > v0) { v1 = v0; i1 = i0; v0 = v; i0 = e; }
        else if (v > v1) { v1 = v; i1 = e; }
    }
    // softmax over the two selected logits (v0 >= v1)
    float w0 = 1.f / (1.f + __expf(v1 - v0));
    float w1 = 1.f - w0;
    int p0 = atomicAdd(&counts[i0], 1);
    lists[i0 * T_TOKENS + p0] = t * 2 + 0;
    wlists[i0 * T_TOKENS + p0] = w0;
    int p1 = atomicAdd(&counts[i1], 1);
    lists[i1 * T_TOKENS + p1] = t * 2 + 1;
    wlists[i1 * T_TOKENS + p1] = w1;
}

// ---------------- GEMM1: x @ W_gate_up^T, fused dequant + SwiGLU ----------------
// grid: (22 n-tiles of 64 I-cols, 16 m-tiles of 128 rows, 8 experts), 256 thr.
// LDS B tile rows interleave gate/up per 16-row MFMA tile: tile t even->gate,
// odd->up, both for I-col block (t>>1)*16. Each wave (64m x 64n) then holds
// matching gate/up accumulator pairs -> SwiGLU entirely in-register.
__global__ __launch_bounds__(256) void gemm1_kernel(
    const float* __restrict__ x,
    const int*   __restrict__ qw,     // [E][2I][H] int in [0,16)
    const float* __restrict__ sc,     // [E][2I][H/128]
    const int*   __restrict__ counts,
    const int*   __restrict__ lists,
    bf16*        __restrict__ act)    // [2T][I]
{
    const int e   = blockIdx.z;
    const int cnt = counts[e];
    const int m0  = blockIdx.y * 128;
    if (m0 >= cnt) return;
    const int n0 = blockIdx.x * 64;   // base I-column

    __shared__ __align__(16) bf16 Al[128 * 64];
    __shared__ __align__(16) bf16 Bl[128 * 64];
    __shared__ int meta[128];

    const int tid = threadIdx.x;
    if (tid < 128) {
        int m = m0 + tid;
        meta[tid] = lists[e * T_TOKENS + (m < cnt ? m : 0)];
    }
    __syncthreads();

    const int lane = tid & 63;
    const int wv = tid >> 6;
    const int wm = wv >> 1, wn = wv & 1;

    floatx4 acc[4][4];
    #pragma unroll
    for (int i = 0; i < 4; ++i)
        #pragma unroll
        for (int j = 0; j < 4; ++j)
            acc[i][j] = (floatx4){0.f, 0.f, 0.f, 0.f};

    const int srow = tid >> 4;         // 0..15
    const int scol = (tid & 15) * 4;   // 0..60

    for (int k0 = 0; k0 < H_DIM; k0 += 64) {
        // ---- stage A: gather token rows, f32 -> bf16 ----
        #pragma unroll
        for (int it = 0; it < 8; ++it) {
            int r = srow + 16 * it;
            int tok = meta[r] >> 1;
            float4 v = *reinterpret_cast<const float4*>(x + (size_t)tok * H_DIM + k0 + scol);
            bf16x4 bv; bv.x = (bf16)v.x; bv.y = (bf16)v.y; bv.z = (bf16)v.z; bv.w = (bf16)v.w;
            *reinterpret_cast<bf16x4*>(&Al[r * 64 + scol]) = bv;
        }
        // ---- stage B: dequant int4 (stored as int32) -> bf16, gate/up interleave ----
        #pragma unroll
        for (int it = 0; it < 8; ++it) {
            int r = srow + 16 * it;
            int tt = r >> 4, within = r & 15;
            int grow = ((tt & 1) ? I_DIM : 0) + n0 + (tt >> 1) * 16 + within;
            const int4 q = *reinterpret_cast<const int4*>(qw + (size_t)(e * 2816 + grow) * H_DIM + k0 + scol);
            float s = sc[(e * 2816 + grow) * 16 + (k0 >> 7)];
            bf16x4 bv;
            bv.x = (bf16)((float)(q.x - 8) * s);
            bv.y = (bf16)((float)(q.y - 8) * s);
            bv.z = (bf16)((float)(q.z - 8) * s);
            bv.w = (bf16)((float)(q.w - 8) * s);
            *reinterpret_cast<bf16x4*>(&Bl[r * 64 + scol]) = bv;
        }
        __syncthreads();
        // ---- compute: 2 k-steps of 32 ----
        #pragma unroll
        for (int ks = 0; ks < 2; ++ks) {
            const int kofs = ks * 32 + (lane >> 4) * 8;
            bf16x8 af[4], bfr[4];
            #pragma unroll
            for (int mt = 0; mt < 4; ++mt)
                af[mt] = *reinterpret_cast<const bf16x8*>(&Al[(wm * 64 + mt * 16 + (lane & 15)) * 64 + kofs]);
            #pragma unroll
            for (int nt = 0; nt < 4; ++nt)
                bfr[nt] = *reinterpret_cast<const bf16x8*>(&Bl[(wn * 64 + nt * 16 + (lane & 15)) * 64 + kofs]);
            #pragma unroll
            for (int mt = 0; mt < 4; ++mt)
                #pragma unroll
                for (int nt = 0; nt < 4; ++nt)
                    acc[mt][nt] = __builtin_amdgcn_mfma_f32_16x16x32_bf16(af[mt], bfr[nt], acc[mt][nt], 0, 0, 0);
        }
        __syncthreads();
    }

    // ---- epilogue: SwiGLU + scatter to act ----
    const int rbase = (lane >> 4) * 4;
    const int cn = lane & 15;
    #pragma unroll
    for (int mt = 0; mt < 4; ++mt) {
        #pragma unroll
        for (int j = 0; j < 2; ++j) {
            floatx4 g = acc[mt][2 * j];
            floatx4 u = acc[mt][2 * j + 1];
            int col = n0 + wn * 32 + j * 16 + cn;
            #pragma unroll
            for (int r = 0; r < 4; ++r) {
                int lrow = wm * 64 + mt * 16 + rbase + r;
                if (m0 + lrow < cnt) {
                    float gate = g[r], up = u[r];
                    float a = gate / (1.f + __expf(-gate)) * up;
                    act[(size_t)meta[lrow] * I_DIM + col] = (bf16)a;
                }
            }
        }
    }
}

// ---------------- GEMM2: act @ W_down^T, scaled by routing weight ----------------
// grid: (16 n-tiles of 128 H-cols, 16 m-tiles, 8 experts), 256 thr.
__global__ __launch_bounds__(256) void gemm2_kernel(
    const bf16*  __restrict__ act,    // [2T][I]
    const int*   __restrict__ qw,     // [E][H][I]
    const float* __restrict__ sc,     // [E][H][I/128]
    const int*   __restrict__ counts,
    const int*   __restrict__ lists,
    const float* __restrict__ wlists,
    float*       __restrict__ tmp)    // [2T][H]
{
    const int e   = blockIdx.z;
    const int cnt = counts[e];
    const int m0  = blockIdx.y * 128;
    if (m0 >= cnt) return;
    const int n0 = blockIdx.x * 128;  // base H-column

    __shared__ __align__(16) bf16 Al[128 * 64];
    __shared__ __align__(16) bf16 Bl[128 * 64];
    __shared__ int   meta[128];
    __shared__ float wmeta[128];

    const int tid = threadIdx.x;
    if (tid < 128) {
        int m = m0 + tid;
        int mm = (m < cnt) ? m : 0;
        meta[tid]  = lists[e * T_TOKENS + mm];
        wmeta[tid] = wlists[e * T_TOKENS + mm];
    }
    __syncthreads();

    const int lane = tid & 63;
    const int wv = tid >> 6;
    const int wm = wv >> 1, wn = wv & 1;

    floatx4 acc[4][4];
    #pragma unroll
    for (int i = 0; i < 4; ++i)
        #pragma unroll
        for (int j = 0; j < 4; ++j)
            acc[i][j] = (floatx4){0.f, 0.f, 0.f, 0.f};

    const int srow = tid >> 4;
    const int scol = (tid & 15) * 4;

    for (int k0 = 0; k0 < I_DIM; k0 += 64) {
        // ---- stage A: act rows (already bf16) ----
        #pragma unroll
        for (int it = 0; it < 8; ++it) {
            int r = srow + 16 * it;
            bf16x4 v = *reinterpret_cast<const bf16x4*>(act + (size_t)meta[r] * I_DIM + k0 + scol);
            *reinterpret_cast<bf16x4*>(&Al[r * 64 + scol]) = v;
        }
        // ---- stage B: dequant down weights ----
        #pragma unroll
        for (int it = 0; it < 8; ++it) {
            int r = srow + 16 * it;
            int grow = n0 + r;
            const int4 q = *reinterpret_cast<const int4*>(qw + (size_t)(e * H_DIM + grow) * I_DIM + k0 + scol);
            float s = sc[(e * H_DIM + grow) * 11 + (k0 >> 7)];
            bf16x4 bv;
            bv.x = (bf16)((float)(q.x - 8) * s);
            bv.y = (bf16)((float)(q.y - 8) * s);
            bv.z = (bf16)((float)(q.z - 8) * s);
            bv.w = (bf16)((float)(q.w - 8) * s);
            *reinterpret_cast<bf16x4*>(&Bl[r * 64 + scol]) = bv;
        }
        __syncthreads();
        #pragma unroll
        for (int ks = 0; ks < 2; ++ks) {
            const int kofs = ks * 32 + (lane >> 4) * 8;
            bf16x8 af[4], bfr[4];
            #pragma unroll
            for (int mt = 0; mt < 4; ++mt)
                af[mt] = *reinterpret_cast<const bf16x8*>(&Al[(wm * 64 + mt * 16 + (lane & 15)) * 64 + kofs]);
            #pragma unroll
            for (int nt = 0; nt < 4; ++nt)
                bfr[nt] = *reinterpret_cast<const bf16x8*>(&Bl[(wn * 64 + nt * 16 + (lane & 15)) * 64 + kofs]);
            #pragma unroll
            for (int mt = 0; mt < 4; ++mt)
                #pragma unroll
                for (int nt = 0; nt < 4; ++nt)
                    acc[mt][nt] = __builtin_amdgcn_mfma_f32_16x16x32_bf16(af[mt], bfr[nt], acc[mt][nt], 0, 0, 0);
        }
        __syncthreads();
    }

    const int rbase = (lane >> 4) * 4;
    const int cn = lane & 15;
    #pragma unroll
    for (int mt = 0; mt < 4; ++mt) {
        #pragma unroll
        for (int nt = 0; nt < 4; ++nt) {
            floatx4 v = acc[mt][nt];
            int col = n0 + wn * 64 + nt * 16 + cn;
            #pragma unroll
            for (int r = 0; r < 4; ++r) {
                int lrow = wm * 64 + mt * 16 + rbase + r;
                if (m0 + lrow < cnt) {
                    tmp[(size_t)meta[lrow] * H_DIM + col] = wmeta[lrow] * v[r];
                }
            }
        }
    }
}

// ---------------- finalize: out[t] = tmp[2t] + tmp[2t+1] ----------------
__global__ void finalize_kernel(const float* __restrict__ tmp, float* __restrict__ out)
{
    int i4 = blockIdx.x * blockDim.x + threadIdx.x;  // one float4 per thread
    int t  = i4 >> 9;          // 512 float4 per H-row
    int h  = (i4 & 511) * 4;
    float4 a = *reinterpret_cast<const float4*>(tmp + ((size_t)2 * t) * H_DIM + h);
    float4 b = *reinterpret_cast<const float4*>(tmp + ((size_t)(2 * t + 1)) * H_DIM + h);
    float4 o;
    o.x = a.x + b.x; o.y = a.y + b.y; o.z = a.z + b.z; o.w = a.w + b.w;
    *reinterpret_cast<float4*>(out + (size_t)t * H_DIM + h) = o;
}

extern "C" void kernel_launch(void* const* d_in, const int* in_sizes, int n_in,
                              void* d_out, int out_size, void* d_ws, size_t ws_size,
                              hipStream_t stream)
{
    const float* router_logits = (const float*)d_in[0];
    const float* x             = (const float*)d_in[1];
    const int*   gu_q          = (const int*)d_in[2];
    const float* gu_s          = (const float*)d_in[3];
    const int*   dn_q          = (const int*)d_in[4];
    const float* dn_s          = (const float*)d_in[5];
    float* out = (float*)d_out;

    char* ws = (char*)d_ws;
    int*   counts = (int*)(ws + OFF_COUNTS);
    int*   lists  = (int*)(ws + OFF_LISTS);
    float* wlists = (float*)(ws + OFF_WLISTS);
    bf16*  act    = (bf16*)(ws + OFF_ACT);
    float* tmp    = (float*)(ws + OFF_TMP);

    hipMemsetAsync(counts, 0, E_NUM * sizeof(int), stream);
    router_kernel<<<T_TOKENS / 256, 256, 0, stream>>>(router_logits, counts, lists, wlists);
    gemm1_kernel<<<dim3(22, 16, 8), 256, 0, stream>>>(x, gu_q, gu_s, counts, lists, act);
    gemm2_kernel<<<dim3(16, 16, 8), 256, 0, stream>>>(act, dn_q, dn_s, counts, lists, wlists, tmp);
    finalize_kernel<<<4096, 256, 0, stream>>>(tmp, out);
}